// Round 10
// baseline (179.334 us; speedup 1.0000x reference)
//
#include <hip/hip_runtime.h>
#include <hip/hip_bf16.h>

#define H 768
#define NH 12
#define DH 64
#define LL 8
#define NTOK 16384   // B*S = 8*2048
#define NREL 100
#define NRELP 128    // padded rows for the K/V-table GEMM
#define PADW 72      // attn LDS row stride in bf16 (144 B = 9 x 16B chunks)

typedef __attribute__((ext_vector_type(8))) short short8;
typedef __attribute__((ext_vector_type(4))) float f32x4;

__device__ __forceinline__ float bf2f(ushort u) {
  union { unsigned int i; float f; } v; v.i = ((unsigned int)u) << 16; return v.f;
}
__device__ __forceinline__ float bflo(unsigned int u) {
  union { unsigned int i; float f; } v; v.i = u << 16; return v.f;
}
__device__ __forceinline__ float bfhi(unsigned int u) {
  union { unsigned int i; float f; } v; v.i = u & 0xffff0000u; return v.f;
}
__device__ __forceinline__ ushort f2bf(float f) {
  union { float f; unsigned int i; } v; v.f = f;
  unsigned int x = v.i;
  return (ushort)((x + 0x7fffu + ((x >> 16) & 1u)) >> 16);  // RNE
}
// HW packed f32->bf16 (RNE); lo = S0, hi = S1 [guide T12 recipe, m214v22]
__device__ __forceinline__ unsigned int cvt_pk_bf16(float lo, float hi) {
  unsigned int r;
  asm("v_cvt_pk_bf16_f32 %0, %1, %2" : "=v"(r) : "v"(lo), "v"(hi));
  return r;
}

// ---------- prep: z<4 -> weight transpose [H][H] f32->bf16; z=4 -> rel cvt
__global__ __launch_bounds__(256) void prep_kernel(
    const float* __restrict__ s0, ushort* __restrict__ d0,
    const float* __restrict__ s1, ushort* __restrict__ d1,
    const float* __restrict__ s2, ushort* __restrict__ d2,
    const float* __restrict__ s3, ushort* __restrict__ d3,
    const float* __restrict__ rel, ushort* __restrict__ RelB) {
  if (blockIdx.z == 4) {
    int b = blockIdx.y * 24 + blockIdx.x;
    if (b < 96) {                                  // 96*1024 = NRELP*H
      int i = (b * 256 + threadIdx.x) * 4;         // 4-chunk stays within a row
      int row = i / H;
      ushort4 o = {0, 0, 0, 0};
      if (row < NREL) {
        float4 v = *(const float4*)(rel + i);
        o.x = f2bf(v.x); o.y = f2bf(v.y); o.z = f2bf(v.z); o.w = f2bf(v.w);
      }
      *(ushort4*)(RelB + i) = o;
    }
    return;
  }
  const float* src; ushort* dst;
  switch (blockIdx.z) {
    case 0:  src = s0; dst = d0; break;
    case 1:  src = s1; dst = d1; break;
    case 2:  src = s2; dst = d2; break;
    default: src = s3; dst = d3; break;
  }
  __shared__ float tile[32][33];
  int bx = blockIdx.x * 32, by = blockIdx.y * 32;
  int tx = threadIdx.x & 31, ty = threadIdx.x >> 5;  // ty 0..7
  #pragma unroll
  for (int i = 0; i < 32; i += 8)
    tile[ty + i][tx] = src[(size_t)(by + ty + i) * H + bx + tx];
  __syncthreads();
  #pragma unroll
  for (int i = 0; i < 32; i += 8)
    dst[(size_t)(bx + ty + i) * H + by + tx] = f2bf(tile[tx][ty + i]);
}

// ------------------------------------------------------------- bf16 MFMA GEMM
// C[M][N] = A[M][K] @ Bt[N][K]^T + bias. BM=64 x BN=128, BK=64.
// A-operand: DIRECT global->register (no LDS; MFMA frag layout maps to
// row-major 16B reads, 16 rows x 64B per instr = cache-line granular),
// prefetched one full K-tile ahead — the per-tile barrier drain COMPLETES the
// prefetch instead of exposing it. B (L2-hot weights): gload_lds, double-
// buffered 2x16KB, XOR-swizzled (T2 both-sides, involution s^(r&7)).
__device__ __forceinline__ void gload_lds16(const void* g, void* l) {
  __builtin_amdgcn_global_load_lds(
      (const __attribute__((address_space(1))) unsigned int*)g,
      (__attribute__((address_space(3))) unsigned int*)l, 16, 0, 0);
}

#define BM 64
#define BN 128
#define BK 64
#define BTILE (BN * BK)   // 8192 ushort = 16 KB

#define STAGE_B(k0, buf)                                                       \
  _Pragma("unroll")                                                            \
  for (int i = 0; i < 4; ++i) {                                                \
    int c = tid + i * 256; int r = c >> 3, sgl = c & 7; int g = sgl ^ (r & 7); \
    gload_lds16(Bt + (size_t)(col0 + r) * K + (k0) + g * 8,                    \
                (char*)Bs + (buf) * (BTILE * 2) + c * 16);                     \
  }

#define GEMM_COMPUTE(cb, AF)                                                   \
  _Pragma("unroll")                                                            \
  for (int kk = 0; kk < 2; ++kk) {                                             \
    const int sw = (((kk << 2) | lk) ^ (lr & 7)) * 8;                          \
    short8 bfr[4];                                                             \
    _Pragma("unroll")                                                          \
    for (int n = 0; n < 4; ++n)                                                \
      bfr[n] = *(const short8*)(Bs + (cb) * BTILE + (wc * 64 + n * 16 + lr) * BK + sw); \
    _Pragma("unroll")                                                          \
    for (int m = 0; m < 2; ++m)                                                \
      _Pragma("unroll")                                                        \
      for (int n = 0; n < 4; ++n)                                              \
        acc[m][n] = __builtin_amdgcn_mfma_f32_16x16x32_bf16(AF[m][kk], bfr[n], \
                                                            acc[m][n], 0, 0, 0);\
  }

#define GEMM_EPILOGUE()                                                        \
  _Pragma("unroll")                                                            \
  for (int m = 0; m < 2; ++m) {                                                \
    _Pragma("unroll")                                                          \
    for (int n = 0; n < 4; ++n) {                                              \
      int col = col0 + wc * 64 + n * 16 + lr;                                  \
      float b = bias[col];                                                     \
      _Pragma("unroll")                                                        \
      for (int j = 0; j < 4; ++j) {                                            \
        int row = row0 + wr * 32 + m * 16 + lk * 4 + j;                        \
        C[(size_t)row * N + col] = f2bf(acc[m][n][j] + b);                     \
      }                                                                        \
    }                                                                          \
  }

// bf16-A variant (OutProj, K/V tables)
__device__ __forceinline__ void gemm_body(
    ushort* Bs,                       // [2][BTILE]
    const ushort* __restrict__ A,     // [M][K] bf16
    const ushort* __restrict__ Bt,    // [N][K] bf16
    const float* __restrict__ bias,
    ushort* __restrict__ C,           // [M][N] bf16
    int M, int N, int K, int bx, int by) {
  const int tid = threadIdx.x;
  const int row0 = by * BM;
  const int col0 = bx * BN;
  const int wave = tid >> 6;
  const int lane = tid & 63;
  const int wr = wave >> 1, wc = wave & 1;
  const int lr = lane & 15, lk = lane >> 4;
  f32x4 acc[2][4];
  #pragma unroll
  for (int m = 0; m < 2; ++m)
    #pragma unroll
    for (int n = 0; n < 4; ++n) acc[m][n] = (f32x4)(0.f);

  const int nt = K / BK;
  const ushort* arow0 = A + (size_t)(row0 + wr * 32 + lr) * K + lk * 8;
  const ushort* arow1 = arow0 + (size_t)16 * K;

  STAGE_B(0, 0)
  short8 curA[2][2];                  // [m][kk]
  curA[0][0] = *(const short8*)(arow0);
  curA[0][1] = *(const short8*)(arow0 + 32);
  curA[1][0] = *(const short8*)(arow1);
  curA[1][1] = *(const short8*)(arow1 + 32);
  __syncthreads();
  int cb = 0;
  for (int t = 0; t < nt; ++t) {
    short8 nxtA[2][2];
    if (t + 1 < nt) {
      int k1 = (t + 1) * BK;
      STAGE_B(k1, cb ^ 1)
      nxtA[0][0] = *(const short8*)(arow0 + k1);
      nxtA[0][1] = *(const short8*)(arow0 + k1 + 32);
      nxtA[1][0] = *(const short8*)(arow1 + k1);
      nxtA[1][1] = *(const short8*)(arow1 + k1 + 32);
    }
    GEMM_COMPUTE(cb, curA)
    __syncthreads();                  // drains B(t+1) + A(t+1) in-flight loads
    cb ^= 1;
    if (t + 1 < nt) {
      curA[0][0] = nxtA[0][0]; curA[0][1] = nxtA[0][1];
      curA[1][0] = nxtA[1][0]; curA[1][1] = nxtA[1][1];
    }
  }
  GEMM_EPILOGUE()
}

// f32-A variant (Q-GEMM, fused X->bf16 cvt at use)
__device__ __forceinline__ void gemm_body_a32(
    ushort* Bs,
    const float* __restrict__ A32,    // [M][K] f32
    const ushort* __restrict__ Bt,    // [N][K] bf16
    const float* __restrict__ bias,
    ushort* __restrict__ C,
    int M, int N, int K, int bx, int by) {
  const int tid = threadIdx.x;
  const int row0 = by * BM;
  const int col0 = bx * BN;
  const int wave = tid >> 6;
  const int lane = tid & 63;
  const int wr = wave >> 1, wc = wave & 1;
  const int lr = lane & 15, lk = lane >> 4;
  f32x4 acc[2][4];
  #pragma unroll
  for (int m = 0; m < 2; ++m)
    #pragma unroll
    for (int n = 0; n < 4; ++n) acc[m][n] = (f32x4)(0.f);

  const int nt = K / BK;
  const float* arow0 = A32 + (size_t)(row0 + wr * 32 + lr) * K + lk * 8;
  const float* arow1 = arow0 + (size_t)16 * K;

  STAGE_B(0, 0)
  float4 curF[2][2][2];               // [m][kk][half]
  #pragma unroll
  for (int kk = 0; kk < 2; ++kk) {
    curF[0][kk][0] = *(const float4*)(arow0 + kk * 32);
    curF[0][kk][1] = *(const float4*)(arow0 + kk * 32 + 4);
    curF[1][kk][0] = *(const float4*)(arow1 + kk * 32);
    curF[1][kk][1] = *(const float4*)(arow1 + kk * 32 + 4);
  }
  __syncthreads();
  int cb = 0;
  for (int t = 0; t < nt; ++t) {
    float4 nxtF[2][2][2];
    if (t + 1 < nt) {
      int k1 = (t + 1) * BK;
      STAGE_B(k1, cb ^ 1)
      #pragma unroll
      for (int kk = 0; kk < 2; ++kk) {
        nxtF[0][kk][0] = *(const float4*)(arow0 + k1 + kk * 32);
        nxtF[0][kk][1] = *(const float4*)(arow0 + k1 + kk * 32 + 4);
        nxtF[1][kk][0] = *(const float4*)(arow1 + k1 + kk * 32);
        nxtF[1][kk][1] = *(const float4*)(arow1 + k1 + kk * 32 + 4);
      }
    }
    // cvt current A tile f32 -> bf16 fragments (loads already drained)
    short8 curA[2][2];
    #pragma unroll
    for (int m = 0; m < 2; ++m)
      #pragma unroll
      for (int kk = 0; kk < 2; ++kk) {
        union { uint4 u; short8 s8; } cv;
        cv.u.x = cvt_pk_bf16(curF[m][kk][0].x, curF[m][kk][0].y);
        cv.u.y = cvt_pk_bf16(curF[m][kk][0].z, curF[m][kk][0].w);
        cv.u.z = cvt_pk_bf16(curF[m][kk][1].x, curF[m][kk][1].y);
        cv.u.w = cvt_pk_bf16(curF[m][kk][1].z, curF[m][kk][1].w);
        curA[m][kk] = cv.s8;
      }
    GEMM_COMPUTE(cb, curA)
    __syncthreads();
    cb ^= 1;
    if (t + 1 < nt) {
      #pragma unroll
      for (int m = 0; m < 2; ++m)
        #pragma unroll
        for (int kk = 0; kk < 2; ++kk) {
          curF[m][kk][0] = nxtF[m][kk][0];
          curF[m][kk][1] = nxtF[m][kk][1];
        }
    }
  }
  GEMM_EPILOGUE()
}

// ---- combined launch: blocks 0..23 = K/V-table GEMMs (hidden under Q-GEMM),
//      blocks 24..1559 = Q = X(f32) @ WqT^T, XCD-swizzled (1536 % 8 == 0)
__global__ __launch_bounds__(256, 4) void gemm_q_kv_kernel(
    const float* __restrict__ X, const ushort* __restrict__ WqT,
    const float* __restrict__ bq, ushort* __restrict__ Qbf,
    const ushort* __restrict__ RelB,
    const ushort* __restrict__ WkT, const float* __restrict__ bk, ushort* __restrict__ Ktab,
    const ushort* __restrict__ WvT, const float* __restrict__ bv, ushort* __restrict__ Vtab) {
  __shared__ ushort Bs[2 * BTILE];   // 32 KB
  int lin = blockIdx.x;
  if (lin < 24) {
    if (lin < 12)
      gemm_body(Bs, RelB, WkT, bk, Ktab, NRELP, H, H, lin % 6, lin / 6);
    else {
      int l = lin - 12;
      gemm_body(Bs, RelB, WvT, bv, Vtab, NRELP, H, H, l % 6, l / 6);
    }
    return;
  }
  int l2 = lin - 24;                        // 0..1535
  int wg = (l2 & 7) * 192 + (l2 >> 3);      // bijective XCD swizzle
  gemm_body_a32(Bs, X, WqT, bq, Qbf, NTOK, H, H, wg % 6, wg / 6);
}

// big bf16 GEMM (OutProj): XCD-swizzled grid (6 x 256)
__global__ __launch_bounds__(256, 4) void gemm_bt_kernel(
    const ushort* __restrict__ A, const ushort* __restrict__ Bt,
    const float* __restrict__ bias, ushort* __restrict__ C,
    int M, int N, int K) {
  __shared__ ushort Bs[2 * BTILE];
  int lin = blockIdx.y * gridDim.x + blockIdx.x;
  int q = (gridDim.x * gridDim.y) >> 3;
  int wg = (lin & 7) * q + (lin >> 3);
  gemm_body(Bs, A, Bt, bias, C, M, N, K, wg % gridDim.x, wg / gridDim.x);
}

// ---------------------------------------------- gather-form GAT attention (v3)
// One lane per (token, head). K/V head-slices staged once per block in LDS
// (rows 0..99, stride 72 bf16). Zero cross-lane ops, one barrier.
__global__ __launch_bounds__(256) void attn3_kernel(
    const ushort* __restrict__ Q,     // [NTOK][H] bf16
    const ushort* __restrict__ Ktab,  // [NRELP][H] bf16
    const ushort* __restrict__ Vtab,  // [NRELP][H] bf16
    const int* __restrict__ graph,    // [NTOK][LL]
    const int* __restrict__ relid,    // [NTOK][LL]
    ushort* __restrict__ Ctx) {       // [NTOK][H] bf16
  __shared__ __align__(16) ushort Ks[NREL * PADW];  // 14.4 KB
  __shared__ __align__(16) ushort Vs[NREL * PADW];  // 14.4 KB
  const int tid = threadIdx.x;
  const int head = blockIdx.y;
  const int t = blockIdx.x * 256 + tid;

  #pragma unroll
  for (int i = 0; i < 4; ++i) {
    int c = tid + i * 256;
    if (c < NREL * 9) {
      int row = c / 9, slot = c - row * 9;
      int gsx = (slot < 8) ? slot * 8 : 0;       // pad chunk: safe dup
      const size_t src = (size_t)row * H + head * DH + gsx;
      gload_lds16(Ktab + src, (char*)Ks + (size_t)c * 16);
      gload_lds16(Vtab + src, (char*)Vs + (size_t)c * 16);
    }
  }

  const uint4* qp = (const uint4*)(Q + (size_t)t * H + head * DH);
  uint4 qw[8];
  #pragma unroll
  for (int j = 0; j < 8; ++j) qw[j] = qp[j];
  const int4* gp = (const int4*)(graph + (size_t)t * LL);
  const int4* rp = (const int4*)(relid + (size_t)t * LL);
  int4 ga = gp[0], gb = gp[1];
  int4 ra = rp[0], rb = rp[1];
  int gs[8] = {ga.x, ga.y, ga.z, ga.w, gb.x, gb.y, gb.z, gb.w};
  int rid[8] = {ra.x, ra.y, ra.z, ra.w, rb.x, rb.y, rb.z, rb.w};
  int koff[8];
  #pragma unroll
  for (int l = 0; l < 8; ++l) {
    int r = rid[l] < 0 ? 0 : rid[l];
    koff[l] = r * (PADW * 2);
  }

  __syncthreads();

  float s[8];
  #pragma unroll
  for (int l = 0; l < 8; ++l) s[l] = 0.f;
  #pragma unroll
  for (int j = 0; j < 8; ++j) {
    float qf[8];
    qf[0] = bflo(qw[j].x); qf[1] = bfhi(qw[j].x);
    qf[2] = bflo(qw[j].y); qf[3] = bfhi(qw[j].y);
    qf[4] = bflo(qw[j].z); qf[5] = bfhi(qw[j].z);
    qf[6] = bflo(qw[j].w); qf[7] = bfhi(qw[j].w);
    #pragma unroll
    for (int l = 0; l < 8; ++l) {
      uint4 kw = *(const uint4*)((const char*)Ks + koff[l] + j * 16);
      s[l] += qf[0] * bflo(kw.x) + qf[1] * bfhi(kw.x)
            + qf[2] * bflo(kw.y) + qf[3] * bfhi(kw.y)
            + qf[4] * bflo(kw.z) + qf[5] * bfhi(kw.z)
            + qf[6] * bflo(kw.w) + qf[7] * bfhi(kw.w);
    }
  }

  #pragma unroll
  for (int l = 0; l < 8; ++l)
    s[l] = (gs[l] != -1) ? s[l] * 0.125f : -10000.0f;
  float mx = s[0];
  #pragma unroll
  for (int l = 1; l < 8; ++l) mx = fmaxf(mx, s[l]);
  float p[8], den = 0.f;
  #pragma unroll
  for (int l = 0; l < 8; ++l) { p[l] = __expf(s[l] - mx); den += p[l]; }
  float inv = 1.f / den;
  #pragma unroll
  for (int l = 0; l < 8; ++l) p[l] *= inv;

  ushort* cp = Ctx + (size_t)t * H + head * DH;
  #pragma unroll
  for (int j = 0; j < 8; ++j) {
    float a[8];
    #pragma unroll
    for (int d = 0; d < 8; ++d) a[d] = 0.f;
    #pragma unroll
    for (int l = 0; l < 8; ++l) {
      uint4 vw = *(const uint4*)((const char*)Vs + koff[l] + j * 16);
      a[0] += p[l] * bflo(vw.x); a[1] += p[l] * bfhi(vw.x);
      a[2] += p[l] * bflo(vw.y); a[3] += p[l] * bfhi(vw.y);
      a[4] += p[l] * bflo(vw.z); a[5] += p[l] * bfhi(vw.z);
      a[6] += p[l] * bflo(vw.w); a[7] += p[l] * bfhi(vw.w);
    }
    short8 o;
    #pragma unroll
    for (int d = 0; d < 8; ++d) o[d] = (short)f2bf(a[d]);
    *(short8*)(cp + j * 8) = o;
  }
}

// ------------------------------------- residual + LayerNorm (192 thr, float4)
__global__ __launch_bounds__(192) void ln_kernel(
    const float* __restrict__ text, const ushort* __restrict__ op,
    const float* __restrict__ gamma, const float* __restrict__ beta,
    float* __restrict__ out) {
  int t = blockIdx.x;
  int c0 = threadIdx.x * 4;
  float4 tv = *(const float4*)(text + (size_t)t * H + c0);
  ushort4 ov = *(const ushort4*)(op + (size_t)t * H + c0);
  float x0 = tv.x + bf2f(ov.x), x1 = tv.y + bf2f(ov.y);
  float x2 = tv.z + bf2f(ov.z), x3 = tv.w + bf2f(ov.w);
  float s = x0 + x1 + x2 + x3;
  float s2 = x0 * x0 + x1 * x1 + x2 * x2 + x3 * x3;
  #pragma unroll
  for (int off = 32; off > 0; off >>= 1) {
    s  += __shfl_xor(s, off, 64);
    s2 += __shfl_xor(s2, off, 64);
  }
  __shared__ float red[2][3];
  int wave = threadIdx.x >> 6, lane = threadIdx.x & 63;
  if (lane == 0) { red[0][wave] = s; red[1][wave] = s2; }
  __syncthreads();
  s  = red[0][0] + red[0][1] + red[0][2];
  s2 = red[1][0] + red[1][1] + red[1][2];
  float mu = s * (1.f / H);
  float var = s2 * (1.f / H) - mu * mu;
  float rs = rsqrtf(var + 1e-5f);
  float4 g4 = *(const float4*)(gamma + c0);
  float4 b4 = *(const float4*)(beta + c0);
  float4 o4;
  o4.x = (x0 - mu) * rs * g4.x + b4.x;
  o4.y = (x1 - mu) * rs * g4.y + b4.y;
  o4.z = (x2 - mu) * rs * g4.z + b4.z;
  o4.w = (x3 - mu) * rs * g4.w + b4.w;
  *(float4*)(out + (size_t)t * H + c0) = o4;
}

// ---------------------------------------------------------------------- driver
extern "C" void kernel_launch(void* const* d_in, const int* in_sizes, int n_in,
                              void* d_out, int out_size, void* d_ws, size_t ws_size,
                              hipStream_t stream) {
  const float* text      = (const float*)d_in[0];
  const int*   graph     = (const int*)d_in[1];
  const int*   relid     = (const int*)d_in[2];
  const float* rel_table = (const float*)d_in[3];
  const float* Wq = (const float*)d_in[4];  const float* bq = (const float*)d_in[5];
  const float* Wk = (const float*)d_in[6];  const float* bk = (const float*)d_in[7];
  const float* Wv = (const float*)d_in[8];  const float* bv = (const float*)d_in[9];
  const float* Wo = (const float*)d_in[10]; const float* bo = (const float*)d_in[11];
  const float* gamma = (const float*)d_in[12];
  const float* beta  = (const float*)d_in[13];
  float* out = (float*)d_out;
  char* ws = (char*)d_ws;

  const size_t TOKH = (size_t)NTOK * H;           // 12,582,912
  size_t off = 0;
  ushort* Ctx  = (ushort*)(ws + off); off += TOKH * 2;             // attn out
  ushort* Qbf  = (ushort*)(ws + off); off += TOKH * 2;             // Q, reused as OutProj
  ushort* WqT  = (ushort*)(ws + off); off += (size_t)H * H * 2;
  ushort* WoT  = (ushort*)(ws + off); off += (size_t)H * H * 2;
  ushort* WkT  = (ushort*)(ws + off); off += (size_t)H * H * 2;
  ushort* WvT  = (ushort*)(ws + off); off += (size_t)H * H * 2;
  ushort* RelB = (ushort*)(ws + off); off += (size_t)NRELP * H * 2;
  ushort* Ktab = (ushort*)(ws + off); off += (size_t)NRELP * H * 2;
  ushort* Vtab = (ushort*)(ws + off); off += (size_t)NRELP * H * 2;

  // 1) weight transposes + rel_table cvt (one launch)
  prep_kernel<<<dim3(24, 24, 5), 256, 0, stream>>>(
      Wq, WqT, Wo, WoT, Wk, WkT, Wv, WvT, rel_table, RelB);
  // 2) Q = X(f32) @ WqT^T + bq  (fused cvt), with K/V-table GEMMs hidden inside
  gemm_q_kv_kernel<<<24 + 1536, 256, 0, stream>>>(
      text, WqT, bq, Qbf, RelB, WkT, bk, Ktab, WvT, bv, Vtab);
  // 3) attention -> Ctx
  dim3 ga(NTOK / 256, NH);
  attn3_kernel<<<ga, 256, 0, stream>>>(Qbf, Ktab, Vtab, graph, relid, Ctx);
  // 4) OutProj = Ctx @ WoT^T + bo (reuse Qbf storage)
  dim3 g1(H / BN, NTOK / BM);
  gemm_bt_kernel<<<g1, 256, 0, stream>>>(Ctx, WoT, bo, Qbf, NTOK, H, H);
  // 5) residual + LayerNorm -> out
  ln_kernel<<<NTOK, 192, 0, stream>>>(text, Qbf, gamma, beta, out);
}

// Round 11
// 101.879 us; speedup vs baseline: 1.7603x; 1.7603x over previous
//
#include <hip/hip_runtime.h>
#include <hip/hip_bf16.h>

#define H 768
#define NH 12
#define DH 64
#define LL 8
#define NTOK 16384   // B*S = 8*2048
#define NREL 100
#define NRELP 128    // padded rows for the K/V-table GEMM
#define PADW 72      // attn LDS row stride in bf16 (144 B = 9 x 16B chunks)

typedef __attribute__((ext_vector_type(8))) short short8;
typedef __attribute__((ext_vector_type(4))) float f32x4;

__device__ __forceinline__ float bf2f(ushort u) {
  union { unsigned int i; float f; } v; v.i = ((unsigned int)u) << 16; return v.f;
}
__device__ __forceinline__ float bflo(unsigned int u) {
  union { unsigned int i; float f; } v; v.i = u << 16; return v.f;
}
__device__ __forceinline__ float bfhi(unsigned int u) {
  union { unsigned int i; float f; } v; v.i = u & 0xffff0000u; return v.f;
}
__device__ __forceinline__ ushort f2bf(float f) {
  union { float f; unsigned int i; } v; v.f = f;
  unsigned int x = v.i;
  return (ushort)((x + 0x7fffu + ((x >> 16) & 1u)) >> 16);  // RNE
}
// HW packed f32->bf16 (RNE); lo = S0, hi = S1 [guide T12 recipe, m214v22]
__device__ __forceinline__ unsigned int cvt_pk_bf16(float lo, float hi) {
  unsigned int r;
  asm("v_cvt_pk_bf16_f32 %0, %1, %2" : "=v"(r) : "v"(lo), "v"(hi));
  return r;
}

// ---------- prep: z<4 -> weight transpose [H][H] f32->bf16; z=4 -> rel cvt
__global__ __launch_bounds__(256) void prep_kernel(
    const float* __restrict__ s0, ushort* __restrict__ d0,
    const float* __restrict__ s1, ushort* __restrict__ d1,
    const float* __restrict__ s2, ushort* __restrict__ d2,
    const float* __restrict__ s3, ushort* __restrict__ d3,
    const float* __restrict__ rel, ushort* __restrict__ RelB) {
  if (blockIdx.z == 4) {
    int b = blockIdx.y * 24 + blockIdx.x;
    if (b < 96) {                                  // 96*1024 = NRELP*H
      int i = (b * 256 + threadIdx.x) * 4;         // 4-chunk stays within a row
      int row = i / H;
      ushort4 o = {0, 0, 0, 0};
      if (row < NREL) {
        float4 v = *(const float4*)(rel + i);
        o.x = f2bf(v.x); o.y = f2bf(v.y); o.z = f2bf(v.z); o.w = f2bf(v.w);
      }
      *(ushort4*)(RelB + i) = o;
    }
    return;
  }
  const float* src; ushort* dst;
  switch (blockIdx.z) {
    case 0:  src = s0; dst = d0; break;
    case 1:  src = s1; dst = d1; break;
    case 2:  src = s2; dst = d2; break;
    default: src = s3; dst = d3; break;
  }
  __shared__ float tile[32][33];
  int bx = blockIdx.x * 32, by = blockIdx.y * 32;
  int tx = threadIdx.x & 31, ty = threadIdx.x >> 5;  // ty 0..7
  #pragma unroll
  for (int i = 0; i < 32; i += 8)
    tile[ty + i][tx] = src[(size_t)(by + ty + i) * H + bx + tx];
  __syncthreads();
  #pragma unroll
  for (int i = 0; i < 32; i += 8)
    dst[(size_t)(bx + ty + i) * H + by + tx] = f2bf(tile[tx][ty + i]);
}

// ------------------------------------------------------------- bf16 MFMA GEMM
// C[M][N] = A[M][K] @ Bt[N][K]^T + bias. BM=128 x BN=256, BK=64 — r6's proven
// single-buffer 2-barrier skeleton with a 2x wider tile: 64 MFMA/wave/K-step
// amortize the fixed per-barrier stage-drain stall. LDS 48 KB single-buffered.
// XOR-swizzled LDS (T2 both-sides): physical 16B slot s of row r holds logical
// k-segment s^(r&7); ds_read applies the same involution.
__device__ __forceinline__ void gload_lds16(const void* g, void* l) {
  __builtin_amdgcn_global_load_lds(
      (const __attribute__((address_space(1))) unsigned int*)g,
      (__attribute__((address_space(3))) unsigned int*)l, 16, 0, 0);
}

#define BM 128
#define BN 256
#define BK 64
#define ATILE (BM * BK)   // 8192 ushort = 16 KB
#define BTILE (BN * BK)   // 16384 ushort = 32 KB

// waves 2x2 over 128x256: wave rows wr*64, cols wc*128; acc[4][8]
#define GEMM_COMPUTE()                                                         \
  _Pragma("unroll")                                                            \
  for (int kk = 0; kk < 2; ++kk) {                                             \
    const int sw = (((kk << 2) | lk) ^ (lr & 7)) * 8;                          \
    short8 af[4], bfr[8];                                                      \
    _Pragma("unroll")                                                          \
    for (int m = 0; m < 4; ++m)                                                \
      af[m] = *(const short8*)(As + (wr * 64 + m * 16 + lr) * BK + sw);        \
    _Pragma("unroll")                                                          \
    for (int n = 0; n < 8; ++n)                                                \
      bfr[n] = *(const short8*)(Bs + (wc * 128 + n * 16 + lr) * BK + sw);      \
    _Pragma("unroll")                                                          \
    for (int m = 0; m < 4; ++m)                                                \
      _Pragma("unroll")                                                        \
      for (int n = 0; n < 8; ++n)                                              \
        acc[m][n] = __builtin_amdgcn_mfma_f32_16x16x32_bf16(af[m], bfr[n],     \
                                                            acc[m][n], 0, 0, 0);\
  }

#define GEMM_EPILOGUE()                                                        \
  _Pragma("unroll")                                                            \
  for (int m = 0; m < 4; ++m) {                                                \
    _Pragma("unroll")                                                          \
    for (int n = 0; n < 8; ++n) {                                              \
      int col = col0 + wc * 128 + n * 16 + lr;                                 \
      float b = bias[col];                                                     \
      _Pragma("unroll")                                                        \
      for (int j = 0; j < 4; ++j) {                                            \
        int row = row0 + wr * 64 + m * 16 + lk * 4 + j;                        \
        C[(size_t)row * N + col] = f2bf(acc[m][n][j] + b);                     \
      }                                                                        \
    }                                                                          \
  }

// bf16-A variant (OutProj, K/V tables)
__device__ __forceinline__ void gemm_body(
    ushort* As, ushort* Bs,
    const ushort* __restrict__ A,     // [M][K] bf16
    const ushort* __restrict__ Bt,    // [N][K] bf16
    const float* __restrict__ bias,
    ushort* __restrict__ C,           // [M][N] bf16
    int M, int N, int K, int bx, int by) {
  const int tid = threadIdx.x;
  const int row0 = by * BM;
  const int col0 = bx * BN;
  const int wave = tid >> 6;
  const int lane = tid & 63;
  const int wr = wave >> 1, wc = wave & 1;
  const int lr = lane & 15, lk = lane >> 4;
  f32x4 acc[4][8];
  #pragma unroll
  for (int m = 0; m < 4; ++m)
    #pragma unroll
    for (int n = 0; n < 8; ++n) acc[m][n] = (f32x4)(0.f);

  for (int k0 = 0; k0 < K; k0 += BK) {
    #pragma unroll
    for (int i = 0; i < 4; ++i) {                 // A: 1024 chunks
      int c = tid + i * 256; int r = c >> 3, s = c & 7; int gsx = s ^ (r & 7);
      gload_lds16(A + (size_t)(row0 + r) * K + k0 + gsx * 8, (char*)As + c * 16);
    }
    #pragma unroll
    for (int i = 0; i < 8; ++i) {                 // B: 2048 chunks
      int c = tid + i * 256; int r = c >> 3, s = c & 7; int gsx = s ^ (r & 7);
      gload_lds16(Bt + (size_t)(col0 + r) * K + k0 + gsx * 8, (char*)Bs + c * 16);
    }
    __syncthreads();
    GEMM_COMPUTE()
    __syncthreads();
  }
  GEMM_EPILOGUE()
}

// A-side = f32 source (fused X->bf16 cvt): reg-stage + cvt_pk + linear ds_write
__device__ __forceinline__ void gemm_body_a32(
    ushort* As, ushort* Bs,
    const float* __restrict__ A32,    // [M][K] f32
    const ushort* __restrict__ Bt,    // [N][K] bf16
    const float* __restrict__ bias,
    ushort* __restrict__ C,
    int M, int N, int K, int bx, int by) {
  const int tid = threadIdx.x;
  const int row0 = by * BM;
  const int col0 = bx * BN;
  const int wave = tid >> 6;
  const int lane = tid & 63;
  const int wr = wave >> 1, wc = wave & 1;
  const int lr = lane & 15, lk = lane >> 4;
  f32x4 acc[4][8];
  #pragma unroll
  for (int m = 0; m < 4; ++m)
    #pragma unroll
    for (int n = 0; n < 8; ++n) acc[m][n] = (f32x4)(0.f);

  for (int k0 = 0; k0 < K; k0 += BK) {
    #pragma unroll
    for (int i = 0; i < 8; ++i) {                 // B async
      int c = tid + i * 256; int r = c >> 3, s = c & 7; int gsx = s ^ (r & 7);
      gload_lds16(Bt + (size_t)(col0 + r) * K + k0 + gsx * 8, (char*)Bs + c * 16);
    }
    #pragma unroll
    for (int i = 0; i < 4; ++i) {                 // A: f32 -> bf16 -> LDS
      int c = tid + i * 256; int r = c >> 3, s = c & 7; int gsx = s ^ (r & 7);
      const float* src = A32 + (size_t)(row0 + r) * K + k0 + gsx * 8;
      float4 f0 = *(const float4*)(src);
      float4 f1 = *(const float4*)(src + 4);
      uint4 w;
      w.x = cvt_pk_bf16(f0.x, f0.y);
      w.y = cvt_pk_bf16(f0.z, f0.w);
      w.z = cvt_pk_bf16(f1.x, f1.y);
      w.w = cvt_pk_bf16(f1.z, f1.w);
      *(uint4*)((char*)As + c * 16) = w;
    }
    __syncthreads();
    GEMM_COMPUTE()
    __syncthreads();
  }
  GEMM_EPILOGUE()
}

// ---- combined launch: blocks 0..5 = K/V-table GEMMs (hidden under Q-GEMM),
//      blocks 6..389 = Q = X(f32) @ WqT^T, XCD-swizzled (384 % 8 == 0)
__global__ __launch_bounds__(256, 2) void gemm_q_kv_kernel(
    const float* __restrict__ X, const ushort* __restrict__ WqT,
    const float* __restrict__ bq, ushort* __restrict__ Qbf,
    const ushort* __restrict__ RelB,
    const ushort* __restrict__ WkT, const float* __restrict__ bk, ushort* __restrict__ Ktab,
    const ushort* __restrict__ WvT, const float* __restrict__ bv, ushort* __restrict__ Vtab) {
  __shared__ ushort As[ATILE];   // 16 KB
  __shared__ ushort Bs[BTILE];   // 32 KB
  int lin = blockIdx.x;
  if (lin < 6) {
    if (lin < 3)
      gemm_body(As, Bs, RelB, WkT, bk, Ktab, NRELP, H, H, lin, 0);
    else
      gemm_body(As, Bs, RelB, WvT, bv, Vtab, NRELP, H, H, lin - 3, 0);
    return;
  }
  int l2 = lin - 6;                         // 0..383
  int wg = (l2 & 7) * 48 + (l2 >> 3);       // bijective XCD swizzle (384 = 48*8)
  gemm_body_a32(As, Bs, X, WqT, bq, Qbf, NTOK, H, H, wg % 3, wg / 3);
}

// big bf16 GEMM (OutProj): XCD-swizzled grid (3 x 128)
__global__ __launch_bounds__(256, 2) void gemm_bt_kernel(
    const ushort* __restrict__ A, const ushort* __restrict__ Bt,
    const float* __restrict__ bias, ushort* __restrict__ C,
    int M, int N, int K) {
  __shared__ ushort As[ATILE];
  __shared__ ushort Bs[BTILE];
  int lin = blockIdx.y * gridDim.x + blockIdx.x;
  int q = (gridDim.x * gridDim.y) >> 3;
  int wg = (lin & 7) * q + (lin >> 3);
  gemm_body(As, Bs, A, Bt, bias, C, M, N, K, wg % gridDim.x, wg / gridDim.x);
}

// ---------------------------------------------- gather-form GAT attention (v3)
// One lane per (token, head). K/V head-slices staged once per block in LDS
// (rows 0..99, stride 72 bf16). Zero cross-lane ops, one barrier.
__global__ __launch_bounds__(256) void attn3_kernel(
    const ushort* __restrict__ Q,     // [NTOK][H] bf16
    const ushort* __restrict__ Ktab,  // [NRELP][H] bf16
    const ushort* __restrict__ Vtab,  // [NRELP][H] bf16
    const int* __restrict__ graph,    // [NTOK][LL]
    const int* __restrict__ relid,    // [NTOK][LL]
    ushort* __restrict__ Ctx) {       // [NTOK][H] bf16
  __shared__ __align__(16) ushort Ks[NREL * PADW];  // 14.4 KB
  __shared__ __align__(16) ushort Vs[NREL * PADW];  // 14.4 KB
  const int tid = threadIdx.x;
  const int head = blockIdx.y;
  const int t = blockIdx.x * 256 + tid;

  #pragma unroll
  for (int i = 0; i < 4; ++i) {
    int c = tid + i * 256;
    if (c < NREL * 9) {
      int row = c / 9, slot = c - row * 9;
      int gsx = (slot < 8) ? slot * 8 : 0;       // pad chunk: safe dup
      const size_t src = (size_t)row * H + head * DH + gsx;
      gload_lds16(Ktab + src, (char*)Ks + (size_t)c * 16);
      gload_lds16(Vtab + src, (char*)Vs + (size_t)c * 16);
    }
  }

  const uint4* qp = (const uint4*)(Q + (size_t)t * H + head * DH);
  uint4 qw[8];
  #pragma unroll
  for (int j = 0; j < 8; ++j) qw[j] = qp[j];
  const int4* gp = (const int4*)(graph + (size_t)t * LL);
  const int4* rp = (const int4*)(relid + (size_t)t * LL);
  int4 ga = gp[0], gb = gp[1];
  int4 ra = rp[0], rb = rp[1];
  int gs[8] = {ga.x, ga.y, ga.z, ga.w, gb.x, gb.y, gb.z, gb.w};
  int rid[8] = {ra.x, ra.y, ra.z, ra.w, rb.x, rb.y, rb.z, rb.w};
  int koff[8];
  #pragma unroll
  for (int l = 0; l < 8; ++l) {
    int r = rid[l] < 0 ? 0 : rid[l];
    koff[l] = r * (PADW * 2);
  }

  __syncthreads();

  float s[8];
  #pragma unroll
  for (int l = 0; l < 8; ++l) s[l] = 0.f;
  #pragma unroll
  for (int j = 0; j < 8; ++j) {
    float qf[8];
    qf[0] = bflo(qw[j].x); qf[1] = bfhi(qw[j].x);
    qf[2] = bflo(qw[j].y); qf[3] = bfhi(qw[j].y);
    qf[4] = bflo(qw[j].z); qf[5] = bfhi(qw[j].z);
    qf[6] = bflo(qw[j].w); qf[7] = bfhi(qw[j].w);
    #pragma unroll
    for (int l = 0; l < 8; ++l) {
      uint4 kw = *(const uint4*)((const char*)Ks + koff[l] + j * 16);
      s[l] += qf[0] * bflo(kw.x) + qf[1] * bfhi(kw.x)
            + qf[2] * bflo(kw.y) + qf[3] * bfhi(kw.y)
            + qf[4] * bflo(kw.z) + qf[5] * bfhi(kw.z)
            + qf[6] * bflo(kw.w) + qf[7] * bfhi(kw.w);
    }
  }

  #pragma unroll
  for (int l = 0; l < 8; ++l)
    s[l] = (gs[l] != -1) ? s[l] * 0.125f : -10000.0f;
  float mx = s[0];
  #pragma unroll
  for (int l = 1; l < 8; ++l) mx = fmaxf(mx, s[l]);
  float p[8], den = 0.f;
  #pragma unroll
  for (int l = 0; l < 8; ++l) { p[l] = __expf(s[l] - mx); den += p[l]; }
  float inv = 1.f / den;
  #pragma unroll
  for (int l = 0; l < 8; ++l) p[l] *= inv;

  ushort* cp = Ctx + (size_t)t * H + head * DH;
  #pragma unroll
  for (int j = 0; j < 8; ++j) {
    float a[8];
    #pragma unroll
    for (int d = 0; d < 8; ++d) a[d] = 0.f;
    #pragma unroll
    for (int l = 0; l < 8; ++l) {
      uint4 vw = *(const uint4*)((const char*)Vs + koff[l] + j * 16);
      a[0] += p[l] * bflo(vw.x); a[1] += p[l] * bfhi(vw.x);
      a[2] += p[l] * bflo(vw.y); a[3] += p[l] * bfhi(vw.y);
      a[4] += p[l] * bflo(vw.z); a[5] += p[l] * bfhi(vw.z);
      a[6] += p[l] * bflo(vw.w); a[7] += p[l] * bfhi(vw.w);
    }
    short8 o;
    #pragma unroll
    for (int d = 0; d < 8; ++d) o[d] = (short)f2bf(a[d]);
    *(short8*)(cp + j * 8) = o;
  }
}

// ------------------------------------- residual + LayerNorm (192 thr, float4)
__global__ __launch_bounds__(192) void ln_kernel(
    const float* __restrict__ text, const ushort* __restrict__ op,
    const float* __restrict__ gamma, const float* __restrict__ beta,
    float* __restrict__ out) {
  int t = blockIdx.x;
  int c0 = threadIdx.x * 4;
  float4 tv = *(const float4*)(text + (size_t)t * H + c0);
  ushort4 ov = *(const ushort4*)(op + (size_t)t * H + c0);
  float x0 = tv.x + bf2f(ov.x), x1 = tv.y + bf2f(ov.y);
  float x2 = tv.z + bf2f(ov.z), x3 = tv.w + bf2f(ov.w);
  float s = x0 + x1 + x2 + x3;
  float s2 = x0 * x0 + x1 * x1 + x2 * x2 + x3 * x3;
  #pragma unroll
  for (int off = 32; off > 0; off >>= 1) {
    s  += __shfl_xor(s, off, 64);
    s2 += __shfl_xor(s2, off, 64);
  }
  __shared__ float red[2][3];
  int wave = threadIdx.x >> 6, lane = threadIdx.x & 63;
  if (lane == 0) { red[0][wave] = s; red[1][wave] = s2; }
  __syncthreads();
  s  = red[0][0] + red[0][1] + red[0][2];
  s2 = red[1][0] + red[1][1] + red[1][2];
  float mu = s * (1.f / H);
  float var = s2 * (1.f / H) - mu * mu;
  float rs = rsqrtf(var + 1e-5f);
  float4 g4 = *(const float4*)(gamma + c0);
  float4 b4 = *(const float4*)(beta + c0);
  float4 o4;
  o4.x = (x0 - mu) * rs * g4.x + b4.x;
  o4.y = (x1 - mu) * rs * g4.y + b4.y;
  o4.z = (x2 - mu) * rs * g4.z + b4.z;
  o4.w = (x3 - mu) * rs * g4.w + b4.w;
  *(float4*)(out + (size_t)t * H + c0) = o4;
}

// ---------------------------------------------------------------------- driver
extern "C" void kernel_launch(void* const* d_in, const int* in_sizes, int n_in,
                              void* d_out, int out_size, void* d_ws, size_t ws_size,
                              hipStream_t stream) {
  const float* text      = (const float*)d_in[0];
  const int*   graph     = (const int*)d_in[1];
  const int*   relid     = (const int*)d_in[2];
  const float* rel_table = (const float*)d_in[3];
  const float* Wq = (const float*)d_in[4];  const float* bq = (const float*)d_in[5];
  const float* Wk = (const float*)d_in[6];  const float* bk = (const float*)d_in[7];
  const float* Wv = (const float*)d_in[8];  const float* bv = (const float*)d_in[9];
  const float* Wo = (const float*)d_in[10]; const float* bo = (const float*)d_in[11];
  const float* gamma = (const float*)d_in[12];
  const float* beta  = (const float*)d_in[13];
  float* out = (float*)d_out;
  char* ws = (char*)d_ws;

  const size_t TOKH = (size_t)NTOK * H;           // 12,582,912
  size_t off = 0;
  ushort* Ctx  = (ushort*)(ws + off); off += TOKH * 2;             // attn out
  ushort* Qbf  = (ushort*)(ws + off); off += TOKH * 2;             // Q, reused as OutProj
  ushort* WqT  = (ushort*)(ws + off); off += (size_t)H * H * 2;
  ushort* WoT  = (ushort*)(ws + off); off += (size_t)H * H * 2;
  ushort* WkT  = (ushort*)(ws + off); off += (size_t)H * H * 2;
  ushort* WvT  = (ushort*)(ws + off); off += (size_t)H * H * 2;
  ushort* RelB = (ushort*)(ws + off); off += (size_t)NRELP * H * 2;
  ushort* Ktab = (ushort*)(ws + off); off += (size_t)NRELP * H * 2;
  ushort* Vtab = (ushort*)(ws + off); off += (size_t)NRELP * H * 2;

  // 1) weight transposes + rel_table cvt (one launch)
  prep_kernel<<<dim3(24, 24, 5), 256, 0, stream>>>(
      Wq, WqT, Wo, WoT, Wk, WkT, Wv, WvT, rel_table, RelB);
  // 2) Q = X(f32) @ WqT^T + bq  (fused cvt), with K/V-table GEMMs hidden inside
  gemm_q_kv_kernel<<<6 + 384, 256, 0, stream>>>(
      text, WqT, bq, Qbf, RelB, WkT, bk, Ktab, WvT, bv, Vtab);
  // 3) attention -> Ctx
  dim3 ga(NTOK / 256, NH);
  attn3_kernel<<<ga, 256, 0, stream>>>(Qbf, Ktab, Vtab, graph, relid, Ctx);
  // 4) OutProj = Ctx @ WoT^T + bo (reuse Qbf storage)
  dim3 g1(H / BN, NTOK / BM);
  gemm_bt_kernel<<<g1, 256, 0, stream>>>(Ctx, WoT, bo, Qbf, NTOK, H, H);
  // 5) residual + LayerNorm -> out
  ln_kernel<<<NTOK, 192, 0, stream>>>(text, Qbf, gamma, beta, out);
}